// Round 6
// baseline (37.086 us; speedup 1.0000x reference)
//
#include <hip/hip_runtime.h>

// CenterLoss: mean_i clip(||x_i - c_{labels[i]}||^2, 1e-12, 1e12)
// N=8192, D=128, M=32000.
// Single dispatch, no memset, no spin. Blocks release-store partials, then
// take a ticket via agent-scope fetch_add on a counter in d_ws. The block
// holding the last ticket of this call ((old+1)%NBLK==0 — true exactly once
// per call for ANY initial counter value, so the unreset/poisoned counter is
// harmless) reduces all partials in a fixed order -> deterministic output.

#define N_ROWS 8192
#define DIM    128
#define NBLK   1024     // 1024 blocks * 4 waves * 2 rows/wave = 8192 rows
#define NTHR   256

__global__ __launch_bounds__(NTHR) void centerloss_ticket(
        const float* __restrict__ x,
        const float* __restrict__ c,
        const int*   __restrict__ labels,
        float* __restrict__ partial,
        unsigned int* __restrict__ ticket,
        float* __restrict__ out) {
    const int lane = threadIdx.x & 63;
    const int wid  = threadIdx.x >> 6;            // wave in block (0..3)
    const int wave = blockIdx.x * 4 + wid;        // 0..4095
    const int half = lane >> 5;                   // which of the wave's 2 rows
    const int l32  = lane & 31;
    const int row  = wave * 2 + half;

    const int lbl = labels[row];
    const float4 xv = *reinterpret_cast<const float4*>(x + (size_t)row * DIM + l32 * 4);
    const float4 cv = *reinterpret_cast<const float4*>(c + (size_t)lbl * DIM + l32 * 4);
    const float d0 = xv.x - cv.x;
    const float d1 = xv.y - cv.y;
    const float d2 = xv.z - cv.z;
    const float d3 = xv.w - cv.w;
    float s = d0 * d0 + d1 * d1 + d2 * d2 + d3 * d3;

    #pragma unroll
    for (int off = 16; off > 0; off >>= 1)
        s += __shfl_down(s, off, 32);
    s = fminf(fmaxf(s, 1e-12f), 1e12f);           // clip per row
    const float sB = __shfl(s, 32, 64);

    __shared__ float lds[4];
    __shared__ int   is_last;
    if (lane == 0) lds[wid] = s + sB;
    __syncthreads();
    if (threadIdx.x == 0) {
        const float p = lds[0] + lds[1] + lds[2] + lds[3];
        __hip_atomic_store(&partial[blockIdx.x], p,
                           __ATOMIC_RELEASE, __HIP_MEMORY_SCOPE_AGENT);
        const unsigned int old = __hip_atomic_fetch_add(
            ticket, 1u, __ATOMIC_ACQ_REL, __HIP_MEMORY_SCOPE_AGENT);
        is_last = ((old + 1u) % (unsigned)NBLK == 0u) ? 1 : 0;
    }
    __syncthreads();

    if (is_last) {
        float t = 0.0f;
        for (int i = threadIdx.x; i < NBLK; i += NTHR) {   // fixed order: 4 iters
            t += __hip_atomic_load(&partial[i],
                                   __ATOMIC_ACQUIRE, __HIP_MEMORY_SCOPE_AGENT);
        }
        #pragma unroll
        for (int off = 32; off > 0; off >>= 1)
            t += __shfl_down(t, off, 64);
        __shared__ float l2[4];
        if (lane == 0) l2[wid] = t;
        __syncthreads();
        if (threadIdx.x == 0)
            out[0] = (l2[0] + l2[1] + l2[2] + l2[3]) * (1.0f / (float)N_ROWS);
    }
}

extern "C" void kernel_launch(void* const* d_in, const int* in_sizes, int n_in,
                              void* d_out, int out_size, void* d_ws, size_t ws_size,
                              hipStream_t stream) {
    const float* x      = (const float*)d_in[0];   // [8192, 128] fp32
    const float* center = (const float*)d_in[1];   // [32000, 128] fp32
    const int*   labels = (const int*)d_in[2];     // [8192] int
    float* out = (float*)d_out;
    float* partial = (float*)d_ws;                           // NBLK floats
    unsigned int* ticket = (unsigned int*)((float*)d_ws + NBLK);  // 1 uint

    centerloss_ticket<<<NBLK, NTHR, 0, stream>>>(x, center, labels,
                                                 partial, ticket, out);
}

// Round 7
// 11.308 us; speedup vs baseline: 3.2796x; 3.2796x over previous
//
#include <hip/hip_runtime.h>

// CenterLoss: mean_i clip(||x_i - c_{labels[i]}||^2, 1e-12, 1e12)
// N=8192, D=128, M=32000.
// Two plain dispatches (all single-dispatch fusion variants measured slower:
// grid.sync 57us, spin 15.7us, memset+atomic 23.7us, ticket 37us vs 12.3us).
// Kernel1: float4 gathers, 2 rows/wave (half-wave per row), 1024 blocks.
// Kernel2: reduce 1024 partials.

#define N_ROWS 8192
#define DIM    128
#define NBLK   1024     // 1024 blocks * 4 waves * 2 rows/wave = 8192 rows
#define NTHR   256

__global__ __launch_bounds__(NTHR) void centerloss_partial(
        const float* __restrict__ x,
        const float* __restrict__ c,
        const int*   __restrict__ labels,
        float* __restrict__ partial) {
    const int lane = threadIdx.x & 63;
    const int wid  = threadIdx.x >> 6;            // wave in block (0..3)
    const int wave = blockIdx.x * 4 + wid;        // 0..4095
    const int half = lane >> 5;                   // which of the wave's 2 rows
    const int l32  = lane & 31;                   // lane within 32-lane row group
    const int row  = wave * 2 + half;

    const int lbl = labels[row];
    const float4 xv = *reinterpret_cast<const float4*>(x + (size_t)row * DIM + l32 * 4);
    const float4 cv = *reinterpret_cast<const float4*>(c + (size_t)lbl * DIM + l32 * 4);
    const float d0 = xv.x - cv.x;
    const float d1 = xv.y - cv.y;
    const float d2 = xv.z - cv.z;
    const float d3 = xv.w - cv.w;
    float s = d0 * d0 + d1 * d1 + d2 * d2 + d3 * d3;

    // reduce within each 32-lane half (one row each)
    #pragma unroll
    for (int off = 16; off > 0; off >>= 1)
        s += __shfl_down(s, off, 32);
    s = fminf(fmaxf(s, 1e-12f), 1e12f);           // clip per row
    const float sB = __shfl(s, 32, 64);           // row-B clipped sum

    __shared__ float lds[4];
    if (lane == 0) lds[wid] = s + sB;
    __syncthreads();
    if (threadIdx.x == 0)
        partial[blockIdx.x] = lds[0] + lds[1] + lds[2] + lds[3];
}

__global__ __launch_bounds__(256) void centerloss_final(
        const float* __restrict__ partial,
        float* __restrict__ out) {
    const int lane = threadIdx.x & 63;
    const int wid  = threadIdx.x >> 6;
    float s = 0.0f;
    #pragma unroll
    for (int i = 0; i < NBLK / 256; ++i)          // 4 coalesced iters
        s += partial[i * 256 + threadIdx.x];
    #pragma unroll
    for (int off = 32; off > 0; off >>= 1)
        s += __shfl_down(s, off, 64);
    __shared__ float lds[4];
    if (lane == 0) lds[wid] = s;
    __syncthreads();
    if (threadIdx.x == 0)
        out[0] = (lds[0] + lds[1] + lds[2] + lds[3]) * (1.0f / (float)N_ROWS);
}

extern "C" void kernel_launch(void* const* d_in, const int* in_sizes, int n_in,
                              void* d_out, int out_size, void* d_ws, size_t ws_size,
                              hipStream_t stream) {
    const float* x      = (const float*)d_in[0];   // [8192, 128] fp32
    const float* center = (const float*)d_in[1];   // [32000, 128] fp32
    const int*   labels = (const int*)d_in[2];     // [8192] int
    float* out     = (float*)d_out;
    float* partial = (float*)d_ws;                 // NBLK floats of scratch

    centerloss_partial<<<NBLK, NTHR, 0, stream>>>(x, center, labels, partial);
    centerloss_final<<<1, 256, 0, stream>>>(partial, out);
}